// Round 9
// baseline (141.616 us; speedup 1.0000x reference)
//
#include <hip/hip_runtime.h>
#include <math.h>

// RoPE_35424890257840: fused 3D-rotation + pair-RoPE on K and Q.
// N=131072 tokens, D=256, S=64, F=18 freqs, P=7*18=126 pairs.
// Layout: 16 threads per token-array item; lane u owns elements 4u..4u+3 of
// each of the four 64-element segments (x,y,z,r). Triple rotation and pair
// rotation are both thread-local -> zero shuffles.
// R8: grid-stride (2048 blocks, 8 items/thread, compile-time trip count,
// unroll 2) so the compiler can software-pipeline next-item loads under the
// current item's trig/FMA chain. K/Q block-split + NT load/store retained.

namespace {

constexpr int kNTok = 131072;
constexpr int kD = 256;
constexpr int kHalfThreads = kNTok * 16;   // 2M items per array
constexpr int kBlocks = 2048;              // total; half K, half Q
constexpr int kThreads = 256;
constexpr int kStride = (kBlocks / 2) * kThreads;  // 262144 -> 8 iterations

typedef float f4 __attribute__((ext_vector_type(4)));

__device__ __forceinline__ f4 ntload(const float* p) {
    return __builtin_nontemporal_load((const f4*)p);
}
__device__ __forceinline__ void ntstore(float* p, f4 v) {
    __builtin_nontemporal_store(v, (f4*)p);
}

template <bool IS_K>
__device__ __forceinline__ void pair_rot(int p, const float* __restrict__ lrow,
                                         const float* __restrict__ freqs,
                                         float& a, float& b) {
    const int j = p / 18;
    const int f = p - j * 18;
    const float ang = lrow[j] * freqs[f];
    float s, c;
    __sincosf(ang, &s, &c);
    if constexpr (IS_K) {
        // Ka2 = c*Ka + s*Kb;  Kb2 = c*Kb - s*Ka2   (uses updated Ka2!)
        float a2 = fmaf(s, b, c * a);
        b = fmaf(-s, a2, c * b);
        a = a2;
    } else {
        // Qa2 = c*Qa - s*Qb;  Qb2 = c*Qb + s*Qa2
        float a2 = fmaf(-s, b, c * a);
        b = fmaf(s, a2, c * b);
        a = a2;
    }
}

template <bool IS_K>
__device__ __forceinline__ void process(const float* __restrict__ in,
                                        float* __restrict__ out,
                                        const float* __restrict__ loc,
                                        const float* __restrict__ freqs,
                                        int n, int u) {
    const size_t row = (size_t)n * kD;
    const float* A = in + row;
    f4 lx = ntload(A + 4 * u);
    f4 ly = ntload(A + 64 + 4 * u);
    f4 lz = ntload(A + 128 + 4 * u);
    f4 lr = ntload(A + 192 + 4 * u);
    float vx[4] = {lx.x, lx.y, lx.z, lx.w};
    float vy[4] = {ly.x, ly.y, ly.z, ly.w};
    float vz[4] = {lz.x, lz.y, lz.z, lz.w};
    float vr[4] = {lr.x, lr.y, lr.z, lr.w};

    const float* lrow = loc + (size_t)n * 7;
    float s4, c4, s5, c5, s6, c6;
    __sincosf(lrow[4], &s4, &c4);
    __sincosf(lrow[5], &s5, &c5);
    __sincosf(lrow[6], &s6, &c6);

    // Stage 1: 3D rotation, componentwise.  rot(A,B,a) = (cA+sB, cB-sA)
    // K: (ky,kz,a6); (kx,kz,a5); (kx,ky,a4)
    // Q: (qx,qy,-a4); (qx,qz,-a5); (qy,qz,-a6)
#pragma unroll
    for (int i = 0; i < 4; ++i) {
        float x = vx[i], y = vy[i], z = vz[i];
        if constexpr (IS_K) {
            float y1 = fmaf(s6, z, c6 * y);
            float z1 = fmaf(-s6, y, c6 * z);
            float x1 = fmaf(s5, z1, c5 * x);
            float z2 = fmaf(-s5, x, c5 * z1);
            vx[i] = fmaf(s4, y1, c4 * x1);
            vy[i] = fmaf(-s4, x1, c4 * y1);
            vz[i] = z2;
        } else {
            float x1 = fmaf(-s4, y, c4 * x);
            float y1 = fmaf(s4, x, c4 * y);
            float x2 = fmaf(-s5, z, c5 * x1);
            float z1 = fmaf(s5, x1, c5 * z);
            vx[i] = x2;
            vy[i] = fmaf(-s6, z1, c6 * y1);
            vz[i] = fmaf(s6, y1, c6 * z1);
        }
    }

    // Stage 2: pair rotation. Segment bases in pair-index space: x:0 y:32 z:64 r:96.
    const int p0 = 2 * u;
    pair_rot<IS_K>(p0,          lrow, freqs, vx[0], vx[1]);
    pair_rot<IS_K>(p0 + 1,      lrow, freqs, vx[2], vx[3]);
    pair_rot<IS_K>(32 + p0,     lrow, freqs, vy[0], vy[1]);
    pair_rot<IS_K>(32 + p0 + 1, lrow, freqs, vy[2], vy[3]);
    pair_rot<IS_K>(64 + p0,     lrow, freqs, vz[0], vz[1]);
    pair_rot<IS_K>(64 + p0 + 1, lrow, freqs, vz[2], vz[3]);
    if (u < 15) {  // pairs 96+2u,97+2u valid only while < 126 (elems 252..255 pass through)
        pair_rot<IS_K>(96 + p0,     lrow, freqs, vr[0], vr[1]);
        pair_rot<IS_K>(96 + p0 + 1, lrow, freqs, vr[2], vr[3]);
    }

    float* O = out + row;
    ntstore(O + 4 * u,       f4{vx[0], vx[1], vx[2], vx[3]});
    ntstore(O + 64 + 4 * u,  f4{vy[0], vy[1], vy[2], vy[3]});
    ntstore(O + 128 + 4 * u, f4{vz[0], vz[1], vz[2], vz[3]});
    ntstore(O + 192 + 4 * u, f4{vr[0], vr[1], vr[2], vr[3]});
}

}  // namespace

__global__ __launch_bounds__(kThreads, 8) void rope_kernel(
    const float* __restrict__ Kin, const float* __restrict__ Qin,
    const float* __restrict__ loc, const float* __restrict__ freqs,
    float* __restrict__ Kout, float* __restrict__ Qout)
{
    // Blocks 0..1023 process K, 1024..2047 process Q (block-uniform split).
    // Grid-stride with compile-time stride -> 8 iterations/thread; unroll 2
    // lets the compiler overlap next-item loads with current-item compute.
    if (blockIdx.x < (kBlocks / 2)) {
        int t = blockIdx.x * kThreads + threadIdx.x;
#pragma unroll 2
        for (int it = 0; it < kHalfThreads / kStride; ++it, t += kStride) {
            process<true>(Kin, Kout, loc, freqs, t >> 4, t & 15);
        }
    } else {
        int t = (blockIdx.x - kBlocks / 2) * kThreads + threadIdx.x;
#pragma unroll 2
        for (int it = 0; it < kHalfThreads / kStride; ++it, t += kStride) {
            process<false>(Qin, Qout, loc, freqs, t >> 4, t & 15);
        }
    }
}

extern "C" void kernel_launch(void* const* d_in, const int* in_sizes, int n_in,
                              void* d_out, int out_size, void* d_ws, size_t ws_size,
                              hipStream_t stream) {
    const float* K     = (const float*)d_in[0];  // keyEmbeddings
    const float* Q     = (const float*)d_in[1];  // queryEmbeddings
    const float* loc   = (const float*)d_in[2];  // locations
    const float* freqs = (const float*)d_in[3];  // freqs
    float* Kout = (float*)d_out;                       // output 0: K
    float* Qout = Kout + (size_t)kNTok * kD;           // output 1: Q

    hipLaunchKernelGGL(rope_kernel, dim3(kBlocks), dim3(kThreads), 0, stream,
                       K, Q, loc, freqs, Kout, Qout);
}

// Round 10
// 89.830 us; speedup vs baseline: 1.5765x; 1.5765x over previous
//
#include <hip/hip_runtime.h>
#include <math.h>

// RoPE_35424890257840: fused 3D-rotation + pair-RoPE on K and Q.
// N=131072 tokens, D=256, S=64, F=18 freqs, P=7*18=126 pairs.
// Layout: 16 threads per token-array; lane u owns elements 4u..4u+3 of each
// of the four 64-element segments (x,y,z,r). Triple rotation (e,e+64,e+128)
// and pair rotation (2p,2p+1) are both thread-local -> zero shuffles.
// R9: REVERT to the R7 structure (one item per thread, 16384 blocks).
// R8's grid-stride software-pipeline regressed 90.2 -> 141.6 us (serialized
// items + register growth); TLP alone saturates the memory system here.
// Final: 90.2 us = 5.71 TB/s = 91% of the measured 6.29 TB/s copy ceiling.

namespace {

constexpr int kNTok = 131072;
constexpr int kD = 256;
constexpr int kHalfThreads = kNTok * 16;  // 2M threads per array

typedef float f4 __attribute__((ext_vector_type(4)));

__device__ __forceinline__ f4 ntload(const float* p) {
    return __builtin_nontemporal_load((const f4*)p);
}
__device__ __forceinline__ void ntstore(float* p, f4 v) {
    __builtin_nontemporal_store(v, (f4*)p);
}

template <bool IS_K>
__device__ __forceinline__ void pair_rot(int p, const float* __restrict__ lrow,
                                         const float* __restrict__ freqs,
                                         float& a, float& b) {
    const int j = p / 18;
    const int f = p - j * 18;
    const float ang = lrow[j] * freqs[f];
    float s, c;
    __sincosf(ang, &s, &c);
    if constexpr (IS_K) {
        // Ka2 = c*Ka + s*Kb;  Kb2 = c*Kb - s*Ka2   (uses updated Ka2!)
        float a2 = fmaf(s, b, c * a);
        b = fmaf(-s, a2, c * b);
        a = a2;
    } else {
        // Qa2 = c*Qa - s*Qb;  Qb2 = c*Qb + s*Qa2
        float a2 = fmaf(-s, b, c * a);
        b = fmaf(s, a2, c * b);
        a = a2;
    }
}

template <bool IS_K>
__device__ __forceinline__ void process(const float* __restrict__ in,
                                        float* __restrict__ out,
                                        const float* __restrict__ loc,
                                        const float* __restrict__ freqs,
                                        int n, int u) {
    const size_t row = (size_t)n * kD;
    const float* A = in + row;
    f4 lx = ntload(A + 4 * u);
    f4 ly = ntload(A + 64 + 4 * u);
    f4 lz = ntload(A + 128 + 4 * u);
    f4 lr = ntload(A + 192 + 4 * u);
    float vx[4] = {lx.x, lx.y, lx.z, lx.w};
    float vy[4] = {ly.x, ly.y, ly.z, ly.w};
    float vz[4] = {lz.x, lz.y, lz.z, lz.w};
    float vr[4] = {lr.x, lr.y, lr.z, lr.w};

    const float* lrow = loc + (size_t)n * 7;
    float s4, c4, s5, c5, s6, c6;
    __sincosf(lrow[4], &s4, &c4);
    __sincosf(lrow[5], &s5, &c5);
    __sincosf(lrow[6], &s6, &c6);

    // Stage 1: 3D rotation, componentwise.  rot(A,B,a) = (cA+sB, cB-sA)
    // K: (ky,kz,a6); (kx,kz,a5); (kx,ky,a4)
    // Q: (qx,qy,-a4); (qx,qz,-a5); (qy,qz,-a6)
#pragma unroll
    for (int i = 0; i < 4; ++i) {
        float x = vx[i], y = vy[i], z = vz[i];
        if constexpr (IS_K) {
            float y1 = fmaf(s6, z, c6 * y);
            float z1 = fmaf(-s6, y, c6 * z);
            float x1 = fmaf(s5, z1, c5 * x);
            float z2 = fmaf(-s5, x, c5 * z1);
            vx[i] = fmaf(s4, y1, c4 * x1);
            vy[i] = fmaf(-s4, x1, c4 * y1);
            vz[i] = z2;
        } else {
            float x1 = fmaf(-s4, y, c4 * x);
            float y1 = fmaf(s4, x, c4 * y);
            float x2 = fmaf(-s5, z, c5 * x1);
            float z1 = fmaf(s5, x1, c5 * z);
            vx[i] = x2;
            vy[i] = fmaf(-s6, z1, c6 * y1);
            vz[i] = fmaf(s6, y1, c6 * z1);
        }
    }

    // Stage 2: pair rotation. Segment bases in pair-index space: x:0 y:32 z:64 r:96.
    const int p0 = 2 * u;
    pair_rot<IS_K>(p0,          lrow, freqs, vx[0], vx[1]);
    pair_rot<IS_K>(p0 + 1,      lrow, freqs, vx[2], vx[3]);
    pair_rot<IS_K>(32 + p0,     lrow, freqs, vy[0], vy[1]);
    pair_rot<IS_K>(32 + p0 + 1, lrow, freqs, vy[2], vy[3]);
    pair_rot<IS_K>(64 + p0,     lrow, freqs, vz[0], vz[1]);
    pair_rot<IS_K>(64 + p0 + 1, lrow, freqs, vz[2], vz[3]);
    if (u < 15) {  // pairs 96+2u,97+2u valid only while < 126 (elems 252..255 pass through)
        pair_rot<IS_K>(96 + p0,     lrow, freqs, vr[0], vr[1]);
        pair_rot<IS_K>(96 + p0 + 1, lrow, freqs, vr[2], vr[3]);
    }

    float* O = out + row;
    ntstore(O + 4 * u,       f4{vx[0], vx[1], vx[2], vx[3]});
    ntstore(O + 64 + 4 * u,  f4{vy[0], vy[1], vy[2], vy[3]});
    ntstore(O + 128 + 4 * u, f4{vz[0], vz[1], vz[2], vz[3]});
    ntstore(O + 192 + 4 * u, f4{vr[0], vr[1], vr[2], vr[3]});
}

}  // namespace

__global__ __launch_bounds__(256, 8) void rope_kernel(
    const float* __restrict__ Kin, const float* __restrict__ Qin,
    const float* __restrict__ loc, const float* __restrict__ freqs,
    float* __restrict__ Kout, float* __restrict__ Qout)
{
    const int gtid = blockIdx.x * blockDim.x + threadIdx.x;
    // Blocks 0..8191 process K, 8192..16383 process Q: block-uniform split,
    // no lane divergence, half the live registers per path.
    if (gtid < kHalfThreads) {
        const int n = gtid >> 4;
        const int u = gtid & 15;
        process<true>(Kin, Kout, loc, freqs, n, u);
    } else {
        const int t = gtid - kHalfThreads;
        const int n = t >> 4;
        const int u = t & 15;
        process<false>(Qin, Qout, loc, freqs, n, u);
    }
}

extern "C" void kernel_launch(void* const* d_in, const int* in_sizes, int n_in,
                              void* d_out, int out_size, void* d_ws, size_t ws_size,
                              hipStream_t stream) {
    const float* K     = (const float*)d_in[0];  // keyEmbeddings
    const float* Q     = (const float*)d_in[1];  // queryEmbeddings
    const float* loc   = (const float*)d_in[2];  // locations
    const float* freqs = (const float*)d_in[3];  // freqs
    float* Kout = (float*)d_out;                       // output 0: K
    float* Qout = Kout + (size_t)kNTok * kD;           // output 1: Q

    const int threads = 256;
    const int blocks = (2 * kHalfThreads) / threads;   // 16384
    hipLaunchKernelGGL(rope_kernel, dim3(blocks), dim3(threads), 0, stream,
                       K, Q, loc, freqs, Kout, Qout);
}